// Round 8
// baseline (189.034 us; speedup 1.0000x reference)
//
#include <hip/hip_runtime.h>
#include <hip/hip_bf16.h>

typedef float vf4 __attribute__((ext_vector_type(4)));

// Problem constants (SelfAttention decode step)
#define B_    32
#define DIM_  4096
#define TSEQ  2048
#define LASTT 2047
#define NCH   8
#define CHUNK 256            // TSEQ / NCH
#define SCL   0.08838834764831845f   // 1/sqrt(128)
#define KCH   256            // 4096 / 16 K-chunks
#define ROWS1 6144
#define ROWS4 4096

__device__ __forceinline__ float dotv(vf4 a, vf4 b) {
    return fmaf(a[0], b[0], fmaf(a[1], b[1], fmaf(a[2], b[2], a[3] * b[3])));
}

// ---------------------------------------------------------------------------
// Shared GEMM body: tile = 128 rows x 32 batches, K-chunk = 256 (4 BK=64
// tiles). Per-thread 4x4 micro-tile (rows rg+32i, batches bg+8j). LDS layouts
// audited conflict-free. Writes fp32 partials part[kc][grow][b].
// Weights stay NONTEMPORAL: 160 MB of weight stream must not evict the KV
// cache working set from L3 (k2 feeds on L3 retention; r5 FETCH evidence).
// NO cross-block sync anywhere (r5 post-mortem: per-block device fences are
// catastrophic on MI355X).
// ---------------------------------------------------------------------------
__device__ __forceinline__ void gemm_tile_part(
    const float* __restrict__ W, const float* __restrict__ X,
    float* __restrict__ part, int rloc_base, int grow_base,
    int kb0, int kc, int rowsTot) {
    __shared__ __align__(16) vf4 wS[128][17];
    __shared__ __align__(16) vf4 xS[16][33];
    const int tid = threadIdx.x;
    const int rg = tid >> 3, bg = tid & 7;       // compute mapping
    const int sr4 = tid >> 4, swf = tid & 15;    // W staging mapping
    const int sb = tid >> 3, sxf = tid & 7;      // X staging mapping
    float c[4][4] = {};

    for (int tile = 0; tile < 4; ++tile) {
        const int kb4 = (kb0 + tile * 64) >> 2;     // float4 index base
        #pragma unroll
        for (int jj = 0; jj < 8; ++jj) {            // stage W: 128 rows x 16 f4
            const int row = sr4 + 16 * jj;
            wS[row][swf] = __builtin_nontemporal_load(
                ((const vf4*)(W + (size_t)(rloc_base + row) * DIM_)) + kb4 + swf);
        }
        #pragma unroll
        for (int jj = 0; jj < 2; ++jj) {            // stage X: 32 b x 16 f4
            const int f4i = sxf + 8 * jj;
            xS[f4i][sb] = ((const vf4*)(X + (size_t)sb * DIM_))[kb4 + f4i];
        }
        __syncthreads();
        #pragma unroll
        for (int k4 = 0; k4 < 16; ++k4) {
            const vf4 w0 = wS[rg      ][k4];
            const vf4 w1 = wS[rg + 32 ][k4];
            const vf4 w2 = wS[rg + 64 ][k4];
            const vf4 w3 = wS[rg + 96 ][k4];
            const vf4 x0 = xS[k4][bg     ];
            const vf4 x1 = xS[k4][bg + 8 ];
            const vf4 x2 = xS[k4][bg + 16];
            const vf4 x3 = xS[k4][bg + 24];
            #pragma unroll
            for (int cm = 0; cm < 4; ++cm) {
                c[0][0] = fmaf(w0[cm], x0[cm], c[0][0]);
                c[0][1] = fmaf(w0[cm], x1[cm], c[0][1]);
                c[0][2] = fmaf(w0[cm], x2[cm], c[0][2]);
                c[0][3] = fmaf(w0[cm], x3[cm], c[0][3]);
                c[1][0] = fmaf(w1[cm], x0[cm], c[1][0]);
                c[1][1] = fmaf(w1[cm], x1[cm], c[1][1]);
                c[1][2] = fmaf(w1[cm], x2[cm], c[1][2]);
                c[1][3] = fmaf(w1[cm], x3[cm], c[1][3]);
                c[2][0] = fmaf(w2[cm], x0[cm], c[2][0]);
                c[2][1] = fmaf(w2[cm], x1[cm], c[2][1]);
                c[2][2] = fmaf(w2[cm], x2[cm], c[2][2]);
                c[2][3] = fmaf(w2[cm], x3[cm], c[2][3]);
                c[3][0] = fmaf(w3[cm], x0[cm], c[3][0]);
                c[3][1] = fmaf(w3[cm], x1[cm], c[3][1]);
                c[3][2] = fmaf(w3[cm], x2[cm], c[3][2]);
                c[3][3] = fmaf(w3[cm], x3[cm], c[3][3]);
            }
        }
        __syncthreads();
    }
    float* pb = part + (size_t)kc * rowsTot * 32;
    #pragma unroll
    for (int i = 0; i < 4; ++i)
        #pragma unroll
        for (int j = 0; j < 4; ++j)
            pb[(size_t)(grow_base + rg + 32 * i) * 32 + bg + 8 * j] = c[i][j];
}

// K1: QKV projection partials. Grid = 48 rowblocks x 16 K-chunks = 768.
__global__ __launch_bounds__(256) void k1_qkv(
    const float* __restrict__ x,  const float* __restrict__ wq,
    const float* __restrict__ wk, const float* __restrict__ wv,
    float* __restrict__ part) {
    const int rb = blockIdx.x >> 4, kc = blockIdx.x & 15;
    const int rbase = rb * 128;
    const float* W; int rloc;
    if (rbase < 4096)      { W = wq; rloc = rbase; }
    else if (rbase < 5120) { W = wk; rloc = rbase - 4096; }
    else                   { W = wv; rloc = rbase - 5120; }
    gemm_tile_part(W, x, part, rloc, rbase, kc * KCH, kc, ROWS1);
}

// K1b: sum 16 partials + RoPE + scatter to q_ws/k_ws/v_ws. Grid = 384.
__global__ __launch_bounds__(256) void k1b_comb(
    const float* __restrict__ part, const float* __restrict__ fcos,
    const float* __restrict__ fsin, float* __restrict__ q_ws,
    float* __restrict__ k_ws, float* __restrict__ v_ws) {
    const int tid = threadIdx.x;
    const int b = tid & 31;
    const int row0 = (blockIdx.x * 8 + (tid >> 5)) * 2;
    float e = 0.f, o = 0.f;
    #pragma unroll
    for (int kc = 0; kc < 16; ++kc) {
        const float* pb = part + (size_t)kc * (ROWS1 * 32);
        e += pb[(size_t)row0 * 32 + b];
        o += pb[(size_t)(row0 + 1) * 32 + b];
    }
    if (row0 < 5120) {
        const int d = row0 & 127;
        const float cj = fcos[d >> 1], sj = fsin[d >> 1];
        const float re = e * cj - o * sj;
        const float ro = e * sj + o * cj;
        if (row0 < 4096) {
            q_ws[(size_t)b * 4096 + row0]     = re * SCL;
            q_ws[(size_t)b * 4096 + row0 + 1] = ro * SCL;
        } else {
            k_ws[(size_t)b * 1024 + row0 - 4096] = re;
            k_ws[(size_t)b * 1024 + row0 - 4095] = ro;
        }
    } else {
        v_ws[(size_t)b * 1024 + row0 - 5120] = e;
        v_ws[(size_t)b * 1024 + row0 - 5119] = o;
    }
}

// ---------------------------------------------------------------------------
// K2: flash attention partials. Block = (b, g, chunk of 256). 4 waves x 64
// positions. Scores: 8 lanes/position, 2-deep K prefetch. PV: batched-4 V
// loads. KV loads are PLAIN (not nontemporal): r5 FETCH_SIZE=266MB showed L3
// retains ~half the KV across replays; nt hints early eviction and can only
// hurt that. Position 2047 from k_ws/v_ws (inputs never mutated).
// ---------------------------------------------------------------------------
__global__ __launch_bounds__(256) void k2_attn(
    const float* __restrict__ q_ws, const float* __restrict__ k_ws,
    const float* __restrict__ v_ws, const float* __restrict__ cK,
    const float* __restrict__ cV,   float* __restrict__ cws) {
    __shared__ __align__(16) float p_lds[4][260];
    __shared__ __align__(16) float pacc[4][4][128];
    __shared__ float wred[4][4];
    __shared__ float wsum[4][4];
    const int blk = blockIdx.x;
    const int b = blk >> 6, g = (blk >> 3) & 7, c = blk & 7;
    const int tid = threadIdx.x, wave = tid >> 6, lane = tid & 63;
    const int tbase = c * CHUNK + wave * 64;
    const int s = lane & 7, pown = lane >> 3;

    const vf4* qb4 = (const vf4*)(q_ws + ((size_t)b * 32 + g * 4) * 128);
    vf4 q4[4][4];
    #pragma unroll
    for (int r = 0; r < 4; ++r)
        #pragma unroll
        for (int j = 0; j < 4; ++j)
            q4[r][j] = qb4[r * 32 + j * 8 + s];

    const vf4* kwsrow = (const vf4*)(k_ws + ((size_t)b * 8 + g) * 128);
    const vf4* vwsrow = (const vf4*)(v_ws + ((size_t)b * 8 + g) * 128);

    // ---- score phase (2-deep software pipeline) ----
    vf4 kb[4];
    {
        const int t = tbase + pown;
        const vf4* kr = (t == LASTT) ? kwsrow
            : (const vf4*)(cK + (((size_t)b * TSEQ + t) * 8 + g) * 128);
        #pragma unroll
        for (int j = 0; j < 4; ++j)
            kb[j] = kr[j * 8 + s];
    }
    #pragma unroll
    for (int pg = 0; pg < 8; ++pg) {
        vf4 kn[4];
        if (pg < 7) {
            const int t = tbase + (pg + 1) * 8 + pown;
            const vf4* kr = (t == LASTT) ? kwsrow
                : (const vf4*)(cK + (((size_t)b * TSEQ + t) * 8 + g) * 128);
            #pragma unroll
            for (int j = 0; j < 4; ++j)
                kn[j] = kr[j * 8 + s];
        }
        float a0 = 0.f, a1 = 0.f, a2 = 0.f, a3 = 0.f;
        #pragma unroll
        for (int j = 0; j < 4; ++j) {
            a0 += dotv(q4[0][j], kb[j]);
            a1 += dotv(q4[1][j], kb[j]);
            a2 += dotv(q4[2][j], kb[j]);
            a3 += dotv(q4[3][j], kb[j]);
        }
        #pragma unroll
        for (int m = 4; m >= 1; m >>= 1) {
            a0 += __shfl_xor(a0, m); a1 += __shfl_xor(a1, m);
            a2 += __shfl_xor(a2, m); a3 += __shfl_xor(a3, m);
        }
        const int idx = wave * 64 + pg * 8 + pown;
        if (s == 0) p_lds[0][idx] = a0;
        if (s == 1) p_lds[1][idx] = a1;
        if (s == 2) p_lds[2][idx] = a2;
        if (s == 3) p_lds[3][idx] = a3;
        #pragma unroll
        for (int j = 0; j < 4; ++j) kb[j] = kn[j];
    }

    // ---- softmax (wave covers its own 64 positions) ----
    float sc[4];
    #pragma unroll
    for (int r = 0; r < 4; ++r) sc[r] = p_lds[r][wave * 64 + lane];
    #pragma unroll
    for (int r = 0; r < 4; ++r) {
        float m = sc[r];
        #pragma unroll
        for (int msk = 32; msk >= 1; msk >>= 1) m = fmaxf(m, __shfl_xor(m, msk));
        if (lane == 0) wred[wave][r] = m;
    }
    __syncthreads();
    float M[4], S[4];
    #pragma unroll
    for (int r = 0; r < 4; ++r)
        M[r] = fmaxf(fmaxf(wred[0][r], wred[1][r]), fmaxf(wred[2][r], wred[3][r]));
    #pragma unroll
    for (int r = 0; r < 4; ++r) {
        const float p = __expf(sc[r] - M[r]);
        p_lds[r][wave * 64 + lane] = p;
        float su = p;
        #pragma unroll
        for (int msk = 32; msk >= 1; msk >>= 1) su += __shfl_xor(su, msk);
        if (lane == 0) wsum[wave][r] = su;
    }
    __syncthreads();
    #pragma unroll
    for (int r = 0; r < 4; ++r)
        S[r] = wsum[0][r] + wsum[1][r] + wsum[2][r] + wsum[3][r];

    // ---- PV phase (batched-4 V loads; compiler schedules loads ahead) ----
    const int h = lane >> 5, col = lane & 31;
    float a[4][4] = {};
    #pragma unroll
    for (int tt = 0; tt < 8; ++tt) {
        vf4 vv[4];
        #pragma unroll
        for (int u = 0; u < 4; ++u) {
            const int t = tbase + tt * 8 + u * 2 + h;
            const vf4* vp = (t == LASTT) ? vwsrow
                : (const vf4*)(cV + (((size_t)b * TSEQ + t) * 8 + g) * 128);
            vv[u] = vp[col];
        }
        #pragma unroll
        for (int u = 0; u < 4; ++u) {
            #pragma unroll
            for (int r = 0; r < 4; ++r) {
                const float pr = p_lds[r][wave * 64 + tt * 8 + u * 2 + h];
                a[r][0] = fmaf(pr, vv[u][0], a[r][0]);
                a[r][1] = fmaf(pr, vv[u][1], a[r][1]);
                a[r][2] = fmaf(pr, vv[u][2], a[r][2]);
                a[r][3] = fmaf(pr, vv[u][3], a[r][3]);
            }
        }
    }
    #pragma unroll
    for (int r = 0; r < 4; ++r)
        #pragma unroll
        for (int j = 0; j < 4; ++j) a[r][j] += __shfl_xor(a[r][j], 32);
    if (lane < 32) {
        #pragma unroll
        for (int r = 0; r < 4; ++r) {
            vf4 v; v[0] = a[r][0]; v[1] = a[r][1]; v[2] = a[r][2]; v[3] = a[r][3];
            *(vf4*)&pacc[wave][r][col * 4] = v;
        }
    }
    __syncthreads();
    const size_t base = (size_t)blk * 520;
    for (int o = tid; o < 512; o += 256) {
        const int r = o >> 7, d = o & 127;
        cws[base + r * 130 + d] =
            pacc[0][r][d] + pacc[1][r][d] + pacc[2][r][d] + pacc[3][r][d];
    }
    if (tid == 0) {
        #pragma unroll
        for (int r = 0; r < 4; ++r) {
            cws[base + r * 130 + 128] = M[r];
            cws[base + r * 130 + 129] = S[r];
        }
    }
}

// K3: flash combine over 8 chunks. Grid = 256 (b,g); wave = GQA head.
__global__ __launch_bounds__(256) void k3_comb(const float* __restrict__ cws,
                                               float* __restrict__ attn) {
    const int blk = blockIdx.x;       // b*8 + g
    const int b = blk >> 3, g = blk & 7;
    const int tid = threadIdx.x, r = tid >> 6, lane = tid & 63;
    const size_t base0 = (size_t)blk * 8 * 520 + r * 130;
    float mi[8], si[8];
    float Mg = -3.4e38f;
    #pragma unroll
    for (int ci = 0; ci < 8; ++ci) {
        mi[ci] = cws[base0 + (size_t)ci * 520 + 128];
        si[ci] = cws[base0 + (size_t)ci * 520 + 129];
        Mg = fmaxf(Mg, mi[ci]);
    }
    float w[8], Sg = 0.f;
    #pragma unroll
    for (int ci = 0; ci < 8; ++ci) {
        w[ci] = __expf(mi[ci] - Mg);
        Sg = fmaf(si[ci], w[ci], Sg);
    }
    const float inv = 1.f / Sg;
    #pragma unroll
    for (int dd = 0; dd < 2; ++dd) {
        const int d = lane + dd * 64;
        float o = 0.f;
        #pragma unroll
        for (int ci = 0; ci < 8; ++ci)
            o = fmaf(cws[base0 + (size_t)ci * 520 + d], w[ci], o);
        attn[((size_t)b * 32 + g * 4 + r) * 128 + d] = o * inv;
    }
}

// K4: output projection partials. Grid = 32 rowblocks x 16 K-chunks = 512.
__global__ __launch_bounds__(256) void k4_out(
    const float* __restrict__ attn, const float* __restrict__ wo,
    float* __restrict__ part) {
    const int rb = blockIdx.x >> 4, kc = blockIdx.x & 15;
    const int rbase = rb * 128;
    gemm_tile_part(wo, attn, part, rbase, rbase, kc * KCH, kc, ROWS4);
}

// K4b: sum 16 partials -> out. Grid = 512.
__global__ __launch_bounds__(256) void k4b_comb(const float* __restrict__ part,
                                                float* __restrict__ out) {
    const int tid = threadIdx.x;
    const int b = tid & 31;
    const int row = blockIdx.x * 8 + (tid >> 5);
    float acc = 0.f;
    #pragma unroll
    for (int kc = 0; kc < 16; ++kc)
        acc += part[(size_t)kc * (ROWS4 * 32) + (size_t)row * 32 + b];
    out[(size_t)b * 4096 + row] = acc;
}

// ---------------------------------------------------------------------------
// Workspace (floats), region A reused serially (part1 -> cws -> part4):
//   A:    0          3,145,728  (max of 16*6144*32, 2048*520, 16*4096*32)
//   q_ws: 3,145,728    131,072
//   k_ws: 3,276,800     32,768
//   v_ws: 3,309,568     32,768
//   attn: 3,342,336    131,072   => ~13.9 MB total
// ---------------------------------------------------------------------------
extern "C" void kernel_launch(void* const* d_in, const int* in_sizes, int n_in,
                              void* d_out, int out_size, void* d_ws, size_t ws_size,
                              hipStream_t stream) {
    const float* x    = (const float*)d_in[0];
    const float* wq   = (const float*)d_in[1];
    const float* wk   = (const float*)d_in[2];
    const float* wv   = (const float*)d_in[3];
    const float* wo   = (const float*)d_in[4];
    const float* cK   = (const float*)d_in[5];
    const float* cV   = (const float*)d_in[6];
    const float* fcos = (const float*)d_in[7];
    const float* fsin = (const float*)d_in[8];
    float* ws   = (float*)d_ws;
    float* A    = ws;                    // part1 / cws / part4 (serial reuse)
    float* q_ws = ws + 3145728;
    float* k_ws = ws + 3276800;
    float* v_ws = ws + 3309568;
    float* attn = ws + 3342336;
    float* out  = (float*)d_out;

    hipLaunchKernelGGL(k1_qkv,   dim3(768),  dim3(256), 0, stream,
                       x, wq, wk, wv, A);
    hipLaunchKernelGGL(k1b_comb, dim3(384),  dim3(256), 0, stream,
                       A, fcos, fsin, q_ws, k_ws, v_ws);
    hipLaunchKernelGGL(k2_attn,  dim3(2048), dim3(256), 0, stream,
                       q_ws, k_ws, v_ws, cK, cV, A);
    hipLaunchKernelGGL(k3_comb,  dim3(256),  dim3(256), 0, stream, A, attn);
    hipLaunchKernelGGL(k4_out,   dim3(512),  dim3(256), 0, stream, attn, wo, A);
    hipLaunchKernelGGL(k4b_comb, dim3(512),  dim3(256), 0, stream, A, out);
}

// Round 9
// 187.414 us; speedup vs baseline: 1.0086x; 1.0086x over previous
//
#include <hip/hip_runtime.h>
#include <hip/hip_bf16.h>

typedef float vf4 __attribute__((ext_vector_type(4)));

// Problem constants (SelfAttention decode step)
#define B_    32
#define DIM_  4096
#define TSEQ  2048
#define LASTT 2047
#define NCH   32
#define CHUNK 64             // one wave per 64-position chunk
#define CSTR  528            // cws chunk stride in floats (4 heads x 132)
#define RSTR  132            // per-head stride (128 data + m + s + pad2)
#define SCL   0.08838834764831845f   // 1/sqrt(128)
#define KCH   256            // 4096 / 16 K-chunks
#define ROWS1 6144
#define ROWS4 4096

__device__ __forceinline__ float dotv(vf4 a, vf4 b) {
    return fmaf(a[0], b[0], fmaf(a[1], b[1], fmaf(a[2], b[2], a[3] * b[3])));
}

// ---------------------------------------------------------------------------
// Shared GEMM body: tile = 128 rows x 32 batches, K-chunk = 256 (4 BK=64
// tiles). Per-thread 4x4 micro-tile (rows rg+32i, batches bg+8j). LDS layouts
// audited conflict-free. Writes fp32 partials part[kc][grow][b].
// NO cross-block sync (r5: per-block device fences catastrophic on MI355X).
// ---------------------------------------------------------------------------
__device__ __forceinline__ void gemm_tile_part(
    const float* __restrict__ W, const float* __restrict__ X,
    float* __restrict__ part, int rloc_base, int grow_base,
    int kb0, int kc, int rowsTot) {
    __shared__ __align__(16) vf4 wS[128][17];
    __shared__ __align__(16) vf4 xS[16][33];
    const int tid = threadIdx.x;
    const int rg = tid >> 3, bg = tid & 7;       // compute mapping
    const int sr4 = tid >> 4, swf = tid & 15;    // W staging mapping
    const int sb = tid >> 3, sxf = tid & 7;      // X staging mapping
    float c[4][4] = {};

    for (int tile = 0; tile < 4; ++tile) {
        const int kb4 = (kb0 + tile * 64) >> 2;     // float4 index base
        #pragma unroll
        for (int jj = 0; jj < 8; ++jj) {            // stage W: 128 rows x 16 f4
            const int row = sr4 + 16 * jj;
            wS[row][swf] = __builtin_nontemporal_load(
                ((const vf4*)(W + (size_t)(rloc_base + row) * DIM_)) + kb4 + swf);
        }
        #pragma unroll
        for (int jj = 0; jj < 2; ++jj) {            // stage X: 32 b x 16 f4
            const int f4i = sxf + 8 * jj;
            xS[f4i][sb] = ((const vf4*)(X + (size_t)sb * DIM_))[kb4 + f4i];
        }
        __syncthreads();
        #pragma unroll
        for (int k4 = 0; k4 < 16; ++k4) {
            const vf4 w0 = wS[rg      ][k4];
            const vf4 w1 = wS[rg + 32 ][k4];
            const vf4 w2 = wS[rg + 64 ][k4];
            const vf4 w3 = wS[rg + 96 ][k4];
            const vf4 x0 = xS[k4][bg     ];
            const vf4 x1 = xS[k4][bg + 8 ];
            const vf4 x2 = xS[k4][bg + 16];
            const vf4 x3 = xS[k4][bg + 24];
            #pragma unroll
            for (int cm = 0; cm < 4; ++cm) {
                c[0][0] = fmaf(w0[cm], x0[cm], c[0][0]);
                c[0][1] = fmaf(w0[cm], x1[cm], c[0][1]);
                c[0][2] = fmaf(w0[cm], x2[cm], c[0][2]);
                c[0][3] = fmaf(w0[cm], x3[cm], c[0][3]);
                c[1][0] = fmaf(w1[cm], x0[cm], c[1][0]);
                c[1][1] = fmaf(w1[cm], x1[cm], c[1][1]);
                c[1][2] = fmaf(w1[cm], x2[cm], c[1][2]);
                c[1][3] = fmaf(w1[cm], x3[cm], c[1][3]);
                c[2][0] = fmaf(w2[cm], x0[cm], c[2][0]);
                c[2][1] = fmaf(w2[cm], x1[cm], c[2][1]);
                c[2][2] = fmaf(w2[cm], x2[cm], c[2][2]);
                c[2][3] = fmaf(w2[cm], x3[cm], c[2][3]);
                c[3][0] = fmaf(w3[cm], x0[cm], c[3][0]);
                c[3][1] = fmaf(w3[cm], x1[cm], c[3][1]);
                c[3][2] = fmaf(w3[cm], x2[cm], c[3][2]);
                c[3][3] = fmaf(w3[cm], x3[cm], c[3][3]);
            }
        }
        __syncthreads();
    }
    float* pb = part + (size_t)kc * rowsTot * 32;
    #pragma unroll
    for (int i = 0; i < 4; ++i)
        #pragma unroll
        for (int j = 0; j < 4; ++j)
            pb[(size_t)(grow_base + rg + 32 * i) * 32 + bg + 8 * j] = c[i][j];
}

// K1: QKV projection partials. Grid = 48 rowblocks x 16 K-chunks = 768.
__global__ __launch_bounds__(256) void k1_qkv(
    const float* __restrict__ x,  const float* __restrict__ wq,
    const float* __restrict__ wk, const float* __restrict__ wv,
    float* __restrict__ part) {
    const int rb = blockIdx.x >> 4, kc = blockIdx.x & 15;
    const int rbase = rb * 128;
    const float* W; int rloc;
    if (rbase < 4096)      { W = wq; rloc = rbase; }
    else if (rbase < 5120) { W = wk; rloc = rbase - 4096; }
    else                   { W = wv; rloc = rbase - 5120; }
    gemm_tile_part(W, x, part, rloc, rbase, kc * KCH, kc, ROWS1);
}

// K1b: sum 16 partials + RoPE + scatter to q_ws/k_ws/v_ws. Grid = 384.
__global__ __launch_bounds__(256) void k1b_comb(
    const float* __restrict__ part, const float* __restrict__ fcos,
    const float* __restrict__ fsin, float* __restrict__ q_ws,
    float* __restrict__ k_ws, float* __restrict__ v_ws) {
    const int tid = threadIdx.x;
    const int b = tid & 31;
    const int row0 = (blockIdx.x * 8 + (tid >> 5)) * 2;
    float e = 0.f, o = 0.f;
    #pragma unroll
    for (int kc = 0; kc < 16; ++kc) {
        const float* pb = part + (size_t)kc * (ROWS1 * 32);
        e += pb[(size_t)row0 * 32 + b];
        o += pb[(size_t)(row0 + 1) * 32 + b];
    }
    if (row0 < 5120) {
        const int d = row0 & 127;
        const float cj = fcos[d >> 1], sj = fsin[d >> 1];
        const float re = e * cj - o * sj;
        const float ro = e * sj + o * cj;
        if (row0 < 4096) {
            q_ws[(size_t)b * 4096 + row0]     = re * SCL;
            q_ws[(size_t)b * 4096 + row0 + 1] = ro * SCL;
        } else {
            k_ws[(size_t)b * 1024 + row0 - 4096] = re;
            k_ws[(size_t)b * 1024 + row0 - 4095] = ro;
        }
    } else {
        v_ws[(size_t)b * 1024 + row0 - 5120] = e;
        v_ws[(size_t)b * 1024 + row0 - 5119] = o;
    }
}

// ---------------------------------------------------------------------------
// K2: flash attention partials. Block = (b, g, 4-chunk group); each of the 4
// waves independently owns one 64-position chunk: ZERO __syncthreads (r8
// post-mortem: the two block barriers lockstep the waves' phases and drain
// the load pipe; softmax coupling was the only reason and chunk-local softmax
// is equally valid -- k3 merges 32 chunks). Scores: 8 lanes/position, 2-deep
// K prefetch, NONTEMPORAL loads (r8: removing nt cost +40% on k2). In-wave
// LDS ordering (no barrier) for the p matrix, as r3 already relied on.
// Per-wave direct cws record write. Position 2047 from k_ws/v_ws.
// ---------------------------------------------------------------------------
__global__ __launch_bounds__(256) void k2_attn(
    const float* __restrict__ q_ws, const float* __restrict__ k_ws,
    const float* __restrict__ v_ws, const float* __restrict__ cK,
    const float* __restrict__ cV,   float* __restrict__ cws) {
    __shared__ float p_lds[4][4][64];            // [wave][head][pos]
    const int blk = blockIdx.x;
    const int b = blk >> 6, g = (blk >> 3) & 7, cb = blk & 7;
    const int tid = threadIdx.x, wave = tid >> 6, lane = tid & 63;
    const int c = cb * 4 + wave;                 // this wave's chunk 0..31
    const int tbase = c * CHUNK;
    const int s = lane & 7, pown = lane >> 3;

    const vf4* qb4 = (const vf4*)(q_ws + ((size_t)b * 32 + g * 4) * 128);
    vf4 q4[4][4];
    #pragma unroll
    for (int r = 0; r < 4; ++r)
        #pragma unroll
        for (int j = 0; j < 4; ++j)
            q4[r][j] = qb4[r * 32 + j * 8 + s];

    const vf4* kwsrow = (const vf4*)(k_ws + ((size_t)b * 8 + g) * 128);
    const vf4* vwsrow = (const vf4*)(v_ws + ((size_t)b * 8 + g) * 128);

    // ---- score phase (2-deep software pipeline) ----
    vf4 kb[4];
    {
        const int t = tbase + pown;
        const vf4* kr = (t == LASTT) ? kwsrow
            : (const vf4*)(cK + (((size_t)b * TSEQ + t) * 8 + g) * 128);
        #pragma unroll
        for (int j = 0; j < 4; ++j)
            kb[j] = __builtin_nontemporal_load(&kr[j * 8 + s]);
    }
    #pragma unroll
    for (int pg = 0; pg < 8; ++pg) {
        vf4 kn[4];
        if (pg < 7) {
            const int t = tbase + (pg + 1) * 8 + pown;
            const vf4* kr = (t == LASTT) ? kwsrow
                : (const vf4*)(cK + (((size_t)b * TSEQ + t) * 8 + g) * 128);
            #pragma unroll
            for (int j = 0; j < 4; ++j)
                kn[j] = __builtin_nontemporal_load(&kr[j * 8 + s]);
        }
        float a0 = 0.f, a1 = 0.f, a2 = 0.f, a3 = 0.f;
        #pragma unroll
        for (int j = 0; j < 4; ++j) {
            a0 += dotv(q4[0][j], kb[j]);
            a1 += dotv(q4[1][j], kb[j]);
            a2 += dotv(q4[2][j], kb[j]);
            a3 += dotv(q4[3][j], kb[j]);
        }
        #pragma unroll
        for (int m = 4; m >= 1; m >>= 1) {
            a0 += __shfl_xor(a0, m); a1 += __shfl_xor(a1, m);
            a2 += __shfl_xor(a2, m); a3 += __shfl_xor(a3, m);
        }
        const int idx = pg * 8 + pown;
        if (s == 0) p_lds[wave][0][idx] = a0;
        if (s == 1) p_lds[wave][1][idx] = a1;
        if (s == 2) p_lds[wave][2][idx] = a2;
        if (s == 3) p_lds[wave][3][idx] = a3;
        #pragma unroll
        for (int j = 0; j < 4; ++j) kb[j] = kn[j];
    }

    // ---- softmax (wave-local over its 64 positions; in-wave DS ordering) ----
    float sc[4], M[4], S[4];
    #pragma unroll
    for (int r = 0; r < 4; ++r) sc[r] = p_lds[wave][r][lane];
    #pragma unroll
    for (int r = 0; r < 4; ++r) {
        float m = sc[r];
        #pragma unroll
        for (int msk = 32; msk >= 1; msk >>= 1) m = fmaxf(m, __shfl_xor(m, msk));
        M[r] = m;
        const float p = __expf(sc[r] - m);
        p_lds[wave][r][lane] = p;
        float su = p;
        #pragma unroll
        for (int msk = 32; msk >= 1; msk >>= 1) su += __shfl_xor(su, msk);
        S[r] = su;
    }

    // ---- PV phase (batched-4 nontemporal V loads) ----
    const int h = lane >> 5, col = lane & 31;
    float a[4][4] = {};
    #pragma unroll
    for (int tt = 0; tt < 8; ++tt) {
        vf4 vv[4];
        #pragma unroll
        for (int u = 0; u < 4; ++u) {
            const int t = tbase + tt * 8 + u * 2 + h;
            const vf4* vp = (t == LASTT) ? vwsrow
                : (const vf4*)(cV + (((size_t)b * TSEQ + t) * 8 + g) * 128);
            vv[u] = __builtin_nontemporal_load(&vp[col]);
        }
        #pragma unroll
        for (int u = 0; u < 4; ++u) {
            #pragma unroll
            for (int r = 0; r < 4; ++r) {
                const float pr = p_lds[wave][r][tt * 8 + u * 2 + h];
                a[r][0] = fmaf(pr, vv[u][0], a[r][0]);
                a[r][1] = fmaf(pr, vv[u][1], a[r][1]);
                a[r][2] = fmaf(pr, vv[u][2], a[r][2]);
                a[r][3] = fmaf(pr, vv[u][3], a[r][3]);
            }
        }
    }
    #pragma unroll
    for (int r = 0; r < 4; ++r)
        #pragma unroll
        for (int j = 0; j < 4; ++j) a[r][j] += __shfl_xor(a[r][j], 32);

    float* base = cws + (size_t)(((b * 8 + g) << 5) + c) * CSTR;
    if (lane < 32) {
        #pragma unroll
        for (int r = 0; r < 4; ++r) {
            vf4 v; v[0] = a[r][0]; v[1] = a[r][1]; v[2] = a[r][2]; v[3] = a[r][3];
            *(vf4*)(base + r * RSTR + col * 4) = v;
        }
    }
    if (lane == 0) {
        #pragma unroll
        for (int r = 0; r < 4; ++r) {
            base[r * RSTR + 128] = M[r];
            base[r * RSTR + 129] = S[r];
        }
    }
}

// K3: flash combine over 32 chunks. Grid = 256 (b,g); wave = GQA head.
__global__ __launch_bounds__(256) void k3_comb(const float* __restrict__ cws,
                                               float* __restrict__ attn) {
    const int blk = blockIdx.x;       // b*8 + g
    const int b = blk >> 3, g = blk & 7;
    const int tid = threadIdx.x, r = tid >> 6, lane = tid & 63;
    const float* base0 = cws + (size_t)blk * 32 * CSTR + r * RSTR;
    float mi[32], si[32];
    float Mg = -3.4e38f;
    #pragma unroll
    for (int ci = 0; ci < 32; ++ci) {
        mi[ci] = base0[(size_t)ci * CSTR + 128];
        si[ci] = base0[(size_t)ci * CSTR + 129];
        Mg = fmaxf(Mg, mi[ci]);
    }
    float w[32], Sg = 0.f;
    #pragma unroll
    for (int ci = 0; ci < 32; ++ci) {
        w[ci] = __expf(mi[ci] - Mg);
        Sg = fmaf(si[ci], w[ci], Sg);
    }
    const float inv = 1.f / Sg;
    #pragma unroll
    for (int dd = 0; dd < 2; ++dd) {
        const int d = lane + dd * 64;
        float o = 0.f;
        #pragma unroll
        for (int ci = 0; ci < 32; ++ci)
            o = fmaf(base0[(size_t)ci * CSTR + d], w[ci], o);
        attn[((size_t)b * 32 + g * 4 + r) * 128 + d] = o * inv;
    }
}

// K4: output projection partials. Grid = 32 rowblocks x 16 K-chunks = 512.
__global__ __launch_bounds__(256) void k4_out(
    const float* __restrict__ attn, const float* __restrict__ wo,
    float* __restrict__ part) {
    const int rb = blockIdx.x >> 4, kc = blockIdx.x & 15;
    const int rbase = rb * 128;
    gemm_tile_part(wo, attn, part, rbase, rbase, kc * KCH, kc, ROWS4);
}

// K4b: sum 16 partials -> out. Grid = 512.
__global__ __launch_bounds__(256) void k4b_comb(const float* __restrict__ part,
                                                float* __restrict__ out) {
    const int tid = threadIdx.x;
    const int b = tid & 31;
    const int row = blockIdx.x * 8 + (tid >> 5);
    float acc = 0.f;
    #pragma unroll
    for (int kc = 0; kc < 16; ++kc)
        acc += part[(size_t)kc * (ROWS4 * 32) + (size_t)row * 32 + b];
    out[(size_t)b * 4096 + row] = acc;
}

// ---------------------------------------------------------------------------
// Workspace (floats), region A reused serially (part1 -> cws -> part4):
//   A:    0          4,325,376  (max of 16*6144*32=3.15M, 8192*528=4.33M,
//                                16*4096*32=2.10M)
//   q_ws: 4,325,376    131,072
//   k_ws: 4,456,448     32,768
//   v_ws: 4,489,216     32,768
//   attn: 4,521,984    131,072   => ~18.6 MB total
// ---------------------------------------------------------------------------
extern "C" void kernel_launch(void* const* d_in, const int* in_sizes, int n_in,
                              void* d_out, int out_size, void* d_ws, size_t ws_size,
                              hipStream_t stream) {
    const float* x    = (const float*)d_in[0];
    const float* wq   = (const float*)d_in[1];
    const float* wk   = (const float*)d_in[2];
    const float* wv   = (const float*)d_in[3];
    const float* wo   = (const float*)d_in[4];
    const float* cK   = (const float*)d_in[5];
    const float* cV   = (const float*)d_in[6];
    const float* fcos = (const float*)d_in[7];
    const float* fsin = (const float*)d_in[8];
    float* ws   = (float*)d_ws;
    float* A    = ws;                    // part1 / cws / part4 (serial reuse)
    float* q_ws = ws + 4325376;
    float* k_ws = ws + 4456448;
    float* v_ws = ws + 4489216;
    float* attn = ws + 4521984;
    float* out  = (float*)d_out;

    hipLaunchKernelGGL(k1_qkv,   dim3(768),  dim3(256), 0, stream,
                       x, wq, wk, wv, A);
    hipLaunchKernelGGL(k1b_comb, dim3(384),  dim3(256), 0, stream,
                       A, fcos, fsin, q_ws, k_ws, v_ws);
    hipLaunchKernelGGL(k2_attn,  dim3(2048), dim3(256), 0, stream,
                       q_ws, k_ws, v_ws, cK, cV, A);
    hipLaunchKernelGGL(k3_comb,  dim3(256),  dim3(256), 0, stream, A, attn);
    hipLaunchKernelGGL(k4_out,   dim3(512),  dim3(256), 0, stream, attn, wo, A);
    hipLaunchKernelGGL(k4b_comb, dim3(512),  dim3(256), 0, stream, A, out);
}

// Round 10
// 161.370 us; speedup vs baseline: 1.1714x; 1.1614x over previous
//
#include <hip/hip_runtime.h>
#include <hip/hip_bf16.h>

typedef float vf4 __attribute__((ext_vector_type(4)));

// Problem constants (SelfAttention decode step)
#define B_    32
#define DIM_  4096
#define TSEQ  2048
#define LASTT 2047
#define NCH   8
#define CHUNK 256            // TSEQ / NCH
#define SCL   0.08838834764831845f   // 1/sqrt(128)
#define KS    16             // K-split for projection GEMMs
#define KCH   256            // 4096 / KS
#define ROWS1 6144
#define ROWS4 4096

__device__ __forceinline__ float dotv(vf4 a, vf4 b) {
    return fmaf(a[0], b[0], fmaf(a[1], b[1], fmaf(a[2], b[2], a[3] * b[3])));
}

// ---------------------------------------------------------------------------
// Shared GEMM body: tile = 128 rows x 32 batches, K-chunk = 256 (4 BK=64
// tiles). Per-thread 4x4 micro-tile (rows rg+32i, batches bg+8j) => 2B of
// LDS read per FMA, all LDS reads/writes audited conflict-free (8 distinct
// bank-quads per instruction). Writes fp32 partials part[kc][grow][b].
// This is the r3-measured 160us configuration, restored byte-identical:
// every k2 deviation since (r6-r9) regressed 16-30us.
// ---------------------------------------------------------------------------
__device__ __forceinline__ void gemm_tile_part(
    const float* __restrict__ W, const float* __restrict__ X,
    float* __restrict__ part, int rloc_base, int grow_base,
    int kb0, int kc, int rowsTot) {
    __shared__ __align__(16) vf4 wS[128][17];
    __shared__ __align__(16) vf4 xS[16][33];
    const int tid = threadIdx.x;
    const int rg = tid >> 3, bg = tid & 7;       // compute mapping
    const int sr4 = tid >> 4, swf = tid & 15;    // W staging mapping
    const int sb = tid >> 3, sxf = tid & 7;      // X staging mapping
    float c[4][4] = {};

    for (int tile = 0; tile < 4; ++tile) {
        const int kb4 = (kb0 + tile * 64) >> 2;     // float4 index base
        #pragma unroll
        for (int jj = 0; jj < 8; ++jj) {            // stage W: 128 rows x 16 f4
            const int row = sr4 + 16 * jj;
            wS[row][swf] =
                ((const vf4*)(W + (size_t)(rloc_base + row) * DIM_))[kb4 + swf];
        }
        #pragma unroll
        for (int jj = 0; jj < 2; ++jj) {            // stage X: 32 b x 16 f4
            const int f4i = sxf + 8 * jj;
            xS[f4i][sb] = ((const vf4*)(X + (size_t)sb * DIM_))[kb4 + f4i];
        }
        __syncthreads();
        #pragma unroll
        for (int k4 = 0; k4 < 16; ++k4) {
            const vf4 w0 = wS[rg      ][k4];
            const vf4 w1 = wS[rg + 32 ][k4];
            const vf4 w2 = wS[rg + 64 ][k4];
            const vf4 w3 = wS[rg + 96 ][k4];
            const vf4 x0 = xS[k4][bg     ];
            const vf4 x1 = xS[k4][bg + 8 ];
            const vf4 x2 = xS[k4][bg + 16];
            const vf4 x3 = xS[k4][bg + 24];
            #pragma unroll
            for (int cm = 0; cm < 4; ++cm) {
                c[0][0] = fmaf(w0[cm], x0[cm], c[0][0]);
                c[0][1] = fmaf(w0[cm], x1[cm], c[0][1]);
                c[0][2] = fmaf(w0[cm], x2[cm], c[0][2]);
                c[0][3] = fmaf(w0[cm], x3[cm], c[0][3]);
                c[1][0] = fmaf(w1[cm], x0[cm], c[1][0]);
                c[1][1] = fmaf(w1[cm], x1[cm], c[1][1]);
                c[1][2] = fmaf(w1[cm], x2[cm], c[1][2]);
                c[1][3] = fmaf(w1[cm], x3[cm], c[1][3]);
                c[2][0] = fmaf(w2[cm], x0[cm], c[2][0]);
                c[2][1] = fmaf(w2[cm], x1[cm], c[2][1]);
                c[2][2] = fmaf(w2[cm], x2[cm], c[2][2]);
                c[2][3] = fmaf(w2[cm], x3[cm], c[2][3]);
                c[3][0] = fmaf(w3[cm], x0[cm], c[3][0]);
                c[3][1] = fmaf(w3[cm], x1[cm], c[3][1]);
                c[3][2] = fmaf(w3[cm], x2[cm], c[3][2]);
                c[3][3] = fmaf(w3[cm], x3[cm], c[3][3]);
            }
        }
        __syncthreads();
    }
    float* pb = part + (size_t)kc * rowsTot * 32;
    #pragma unroll
    for (int i = 0; i < 4; ++i)
        #pragma unroll
        for (int j = 0; j < 4; ++j)
            pb[(size_t)(grow_base + rg + 32 * i) * 32 + bg + 8 * j] = c[i][j];
}

// K1: QKV projection partials. Grid = 48 rowblocks x 16 K-chunks = 768.
__global__ __launch_bounds__(256) void k1_qkv(
    const float* __restrict__ x,  const float* __restrict__ wq,
    const float* __restrict__ wk, const float* __restrict__ wv,
    float* __restrict__ part) {
    const int rb = blockIdx.x >> 4, kc = blockIdx.x & 15;
    const int rbase = rb * 128;
    const float* W; int rloc;
    if (rbase < 4096)      { W = wq; rloc = rbase; }
    else if (rbase < 5120) { W = wk; rloc = rbase - 4096; }
    else                   { W = wv; rloc = rbase - 5120; }
    gemm_tile_part(W, x, part, rloc, rbase, kc * KCH, kc, ROWS1);
}

// K1b: sum 16 partials + RoPE + scatter to q_ws/k_ws/v_ws. Grid = 384.
__global__ __launch_bounds__(256) void k1b_comb(
    const float* __restrict__ part, const float* __restrict__ fcos,
    const float* __restrict__ fsin, float* __restrict__ q_ws,
    float* __restrict__ k_ws, float* __restrict__ v_ws) {
    const int tid = threadIdx.x;
    const int b = tid & 31;
    const int row0 = (blockIdx.x * 8 + (tid >> 5)) * 2;
    float e = 0.f, o = 0.f;
    #pragma unroll
    for (int kc = 0; kc < 16; ++kc) {
        const float* pb = part + (size_t)kc * (ROWS1 * 32);
        e += pb[(size_t)row0 * 32 + b];
        o += pb[(size_t)(row0 + 1) * 32 + b];
    }
    if (row0 < 5120) {
        const int d = row0 & 127;
        const float cj = fcos[d >> 1], sj = fsin[d >> 1];
        const float re = e * cj - o * sj;
        const float ro = e * sj + o * cj;
        if (row0 < 4096) {
            q_ws[(size_t)b * 4096 + row0]     = re * SCL;
            q_ws[(size_t)b * 4096 + row0 + 1] = ro * SCL;
        } else {
            k_ws[(size_t)b * 1024 + row0 - 4096] = re;
            k_ws[(size_t)b * 1024 + row0 - 4095] = ro;
        }
    } else {
        v_ws[(size_t)b * 1024 + row0 - 5120] = e;
        v_ws[(size_t)b * 1024 + row0 - 5119] = o;
    }
}

// ---------------------------------------------------------------------------
// K2: flash attention partials. Block = (b, g, chunk of 256). 4 waves x 64
// positions. Scores: 8 lanes/position, 2-deep prefetch, nontemporal K loads.
// Wave-local softmax stats -> block combine. PV: unroll-4 nontemporal V.
// Position 2047 sourced from k_ws/v_ws (inputs never mutated).
// ---------------------------------------------------------------------------
__global__ __launch_bounds__(256) void k2_attn(
    const float* __restrict__ q_ws, const float* __restrict__ k_ws,
    const float* __restrict__ v_ws, const float* __restrict__ cK,
    const float* __restrict__ cV,   float* __restrict__ cws) {
    __shared__ __align__(16) float p_lds[4][260];
    __shared__ __align__(16) float pacc[4][4][128];
    __shared__ float wred[4][4];
    __shared__ float wsum[4][4];
    const int blk = blockIdx.x;
    const int b = blk >> 6, g = (blk >> 3) & 7, c = blk & 7;
    const int tid = threadIdx.x, wave = tid >> 6, lane = tid & 63;
    const int tbase = c * CHUNK + wave * 64;
    const int s = lane & 7, pown = lane >> 3;

    const vf4* qb4 = (const vf4*)(q_ws + ((size_t)b * 32 + g * 4) * 128);
    vf4 q4[4][4];
    #pragma unroll
    for (int r = 0; r < 4; ++r)
        #pragma unroll
        for (int j = 0; j < 4; ++j)
            q4[r][j] = qb4[r * 32 + j * 8 + s];

    const vf4* kwsrow = (const vf4*)(k_ws + ((size_t)b * 8 + g) * 128);
    const vf4* vwsrow = (const vf4*)(v_ws + ((size_t)b * 8 + g) * 128);

    // ---- score phase (2-deep software pipeline) ----
    vf4 kb[4];
    {
        const int t = tbase + pown;
        const vf4* kr = (t == LASTT) ? kwsrow
            : (const vf4*)(cK + (((size_t)b * TSEQ + t) * 8 + g) * 128);
        #pragma unroll
        for (int j = 0; j < 4; ++j)
            kb[j] = __builtin_nontemporal_load(&kr[j * 8 + s]);
    }
    #pragma unroll
    for (int pg = 0; pg < 8; ++pg) {
        vf4 kn[4];
        if (pg < 7) {
            const int t = tbase + (pg + 1) * 8 + pown;
            const vf4* kr = (t == LASTT) ? kwsrow
                : (const vf4*)(cK + (((size_t)b * TSEQ + t) * 8 + g) * 128);
            #pragma unroll
            for (int j = 0; j < 4; ++j)
                kn[j] = __builtin_nontemporal_load(&kr[j * 8 + s]);
        }
        float a0 = 0.f, a1 = 0.f, a2 = 0.f, a3 = 0.f;
        #pragma unroll
        for (int j = 0; j < 4; ++j) {
            a0 += dotv(q4[0][j], kb[j]);
            a1 += dotv(q4[1][j], kb[j]);
            a2 += dotv(q4[2][j], kb[j]);
            a3 += dotv(q4[3][j], kb[j]);
        }
        #pragma unroll
        for (int m = 4; m >= 1; m >>= 1) {
            a0 += __shfl_xor(a0, m); a1 += __shfl_xor(a1, m);
            a2 += __shfl_xor(a2, m); a3 += __shfl_xor(a3, m);
        }
        const int idx = wave * 64 + pg * 8 + pown;
        if (s == 0) p_lds[0][idx] = a0;
        if (s == 1) p_lds[1][idx] = a1;
        if (s == 2) p_lds[2][idx] = a2;
        if (s == 3) p_lds[3][idx] = a3;
        #pragma unroll
        for (int j = 0; j < 4; ++j) kb[j] = kn[j];
    }

    // ---- softmax (wave covers its own 64 positions) ----
    float sc[4];
    #pragma unroll
    for (int r = 0; r < 4; ++r) sc[r] = p_lds[r][wave * 64 + lane];
    #pragma unroll
    for (int r = 0; r < 4; ++r) {
        float m = sc[r];
        #pragma unroll
        for (int msk = 32; msk >= 1; msk >>= 1) m = fmaxf(m, __shfl_xor(m, msk));
        if (lane == 0) wred[wave][r] = m;
    }
    __syncthreads();
    float M[4], S[4];
    #pragma unroll
    for (int r = 0; r < 4; ++r)
        M[r] = fmaxf(fmaxf(wred[0][r], wred[1][r]), fmaxf(wred[2][r], wred[3][r]));
    #pragma unroll
    for (int r = 0; r < 4; ++r) {
        const float p = __expf(sc[r] - M[r]);
        p_lds[r][wave * 64 + lane] = p;
        float su = p;
        #pragma unroll
        for (int msk = 32; msk >= 1; msk >>= 1) su += __shfl_xor(su, msk);
        if (lane == 0) wsum[wave][r] = su;
    }
    __syncthreads();
    #pragma unroll
    for (int r = 0; r < 4; ++r)
        S[r] = wsum[0][r] + wsum[1][r] + wsum[2][r] + wsum[3][r];

    // ---- PV phase ----
    const int h = lane >> 5, col = lane & 31;
    float a[4][4] = {};
    #pragma unroll
    for (int tt = 0; tt < 8; ++tt) {
        vf4 vv[4];
        #pragma unroll
        for (int u = 0; u < 4; ++u) {
            const int t = tbase + tt * 8 + u * 2 + h;
            const vf4* vp = (t == LASTT) ? vwsrow
                : (const vf4*)(cV + (((size_t)b * TSEQ + t) * 8 + g) * 128);
            vv[u] = __builtin_nontemporal_load(&vp[col]);
        }
        #pragma unroll
        for (int u = 0; u < 4; ++u) {
            #pragma unroll
            for (int r = 0; r < 4; ++r) {
                const float pr = p_lds[r][wave * 64 + tt * 8 + u * 2 + h];
                a[r][0] = fmaf(pr, vv[u][0], a[r][0]);
                a[r][1] = fmaf(pr, vv[u][1], a[r][1]);
                a[r][2] = fmaf(pr, vv[u][2], a[r][2]);
                a[r][3] = fmaf(pr, vv[u][3], a[r][3]);
            }
        }
    }
    #pragma unroll
    for (int r = 0; r < 4; ++r)
        #pragma unroll
        for (int j = 0; j < 4; ++j) a[r][j] += __shfl_xor(a[r][j], 32);
    if (lane < 32) {
        #pragma unroll
        for (int r = 0; r < 4; ++r) {
            vf4 v; v[0] = a[r][0]; v[1] = a[r][1]; v[2] = a[r][2]; v[3] = a[r][3];
            *(vf4*)&pacc[wave][r][col * 4] = v;
        }
    }
    __syncthreads();
    const size_t base = (size_t)blk * 520;
    for (int o = tid; o < 512; o += 256) {
        const int r = o >> 7, d = o & 127;
        cws[base + r * 130 + d] =
            pacc[0][r][d] + pacc[1][r][d] + pacc[2][r][d] + pacc[3][r][d];
    }
    if (tid == 0) {
        #pragma unroll
        for (int r = 0; r < 4; ++r) {
            cws[base + r * 130 + 128] = M[r];
            cws[base + r * 130 + 129] = S[r];
        }
    }
}

// K3: flash combine over 8 chunks. Grid = 256 (b,g); wave = GQA head.
__global__ __launch_bounds__(256) void k3_comb(const float* __restrict__ cws,
                                               float* __restrict__ attn) {
    const int blk = blockIdx.x;       // b*8 + g
    const int b = blk >> 3, g = blk & 7;
    const int tid = threadIdx.x, r = tid >> 6, lane = tid & 63;
    const size_t base0 = (size_t)blk * 8 * 520 + r * 130;
    float mi[8], si[8];
    float Mg = -3.4e38f;
    #pragma unroll
    for (int ci = 0; ci < 8; ++ci) {
        mi[ci] = cws[base0 + (size_t)ci * 520 + 128];
        si[ci] = cws[base0 + (size_t)ci * 520 + 129];
        Mg = fmaxf(Mg, mi[ci]);
    }
    float w[8], Sg = 0.f;
    #pragma unroll
    for (int ci = 0; ci < 8; ++ci) {
        w[ci] = __expf(mi[ci] - Mg);
        Sg = fmaf(si[ci], w[ci], Sg);
    }
    const float inv = 1.f / Sg;
    #pragma unroll
    for (int dd = 0; dd < 2; ++dd) {
        const int d = lane + dd * 64;
        float o = 0.f;
        #pragma unroll
        for (int ci = 0; ci < 8; ++ci)
            o = fmaf(cws[base0 + (size_t)ci * 520 + d], w[ci], o);
        attn[((size_t)b * 32 + g * 4 + r) * 128 + d] = o * inv;
    }
}

// K4: output projection partials. Grid = 32 rowblocks x 16 K-chunks = 512.
__global__ __launch_bounds__(256) void k4_out(
    const float* __restrict__ attn, const float* __restrict__ wo,
    float* __restrict__ part) {
    const int rb = blockIdx.x >> 4, kc = blockIdx.x & 15;
    const int rbase = rb * 128;
    gemm_tile_part(wo, attn, part, rbase, rbase, kc * KCH, kc, ROWS4);
}

// K4b: sum 16 partials -> out. Grid = 512.
__global__ __launch_bounds__(256) void k4b_comb(const float* __restrict__ part,
                                                float* __restrict__ out) {
    const int tid = threadIdx.x;
    const int b = tid & 31;
    const int row = blockIdx.x * 8 + (tid >> 5);
    float acc = 0.f;
    #pragma unroll
    for (int kc = 0; kc < 16; ++kc)
        acc += part[(size_t)kc * (ROWS4 * 32) + (size_t)row * 32 + b];
    out[(size_t)b * 4096 + row] = acc;
}

// ---------------------------------------------------------------------------
// Workspace (floats), region A reused serially (part1 -> cws -> part4):
//   A:    offset 0,        3,145,728   (max of 16*6144*32, 2048*520, 16*4096*32)
//   q_ws: 3,145,728        131,072
//   k_ws: 3,276,800         32,768
//   v_ws: 3,309,568         32,768
//   attn: 3,342,336        131,072     => total ~13.9 MB
// ---------------------------------------------------------------------------
extern "C" void kernel_launch(void* const* d_in, const int* in_sizes, int n_in,
                              void* d_out, int out_size, void* d_ws, size_t ws_size,
                              hipStream_t stream) {
    const float* x    = (const float*)d_in[0];
    const float* wq   = (const float*)d_in[1];
    const float* wk   = (const float*)d_in[2];
    const float* wv   = (const float*)d_in[3];
    const float* wo   = (const float*)d_in[4];
    const float* cK   = (const float*)d_in[5];
    const float* cV   = (const float*)d_in[6];
    const float* fcos = (const float*)d_in[7];
    const float* fsin = (const float*)d_in[8];
    float* ws   = (float*)d_ws;
    float* A    = ws;                    // part1 / cws / part4 (serial reuse)
    float* q_ws = ws + 3145728;
    float* k_ws = ws + 3276800;
    float* v_ws = ws + 3309568;
    float* attn = ws + 3342336;
    float* out  = (float*)d_out;

    hipLaunchKernelGGL(k1_qkv,   dim3(768),  dim3(256), 0, stream,
                       x, wq, wk, wv, A);
    hipLaunchKernelGGL(k1b_comb, dim3(384),  dim3(256), 0, stream,
                       A, fcos, fsin, q_ws, k_ws, v_ws);
    hipLaunchKernelGGL(k2_attn,  dim3(2048), dim3(256), 0, stream,
                       q_ws, k_ws, v_ws, cK, cV, A);
    hipLaunchKernelGGL(k3_comb,  dim3(256),  dim3(256), 0, stream, A, attn);
    hipLaunchKernelGGL(k4_out,   dim3(512),  dim3(256), 0, stream, attn, wo, A);
    hipLaunchKernelGGL(k4b_comb, dim3(512),  dim3(256), 0, stream, A, out);
}